// Round 11
// baseline (434.676 us; speedup 1.0000x reference)
//
#include <hip/hip_runtime.h>

#define NN 50000
#define NE 800000
#define HIST_BLOCKS ((NE + 255) / 256)   // 3125
#define FILL_BLOCKS HIST_BLOCKS          // 3125
#define FC_BLOCKS 1024
#define PLANE ((NN + 1) * 32)            // u16 elems per channel-plane (row NN = zeros)

typedef unsigned short u16;
typedef unsigned int u32;

__device__ inline float rlf(float v, int l) {
    return __int_as_float(__builtin_amdgcn_readlane(__float_as_int(v), l));
}
__device__ inline int bperm(int v, int l) {  // v from lane l (l may be VGPR)
    return __builtin_amdgcn_ds_bpermute(l << 2, v);
}
__device__ inline u16 f2bf(float f) {  // round-to-nearest-even
    u32 u = __float_as_uint(f);
    u32 r = (u + 0x7FFFu + ((u >> 16) & 1u)) >> 16;
    return (u16)r;
}
__device__ inline float lo16(u32 q) { return __uint_as_float(q << 16); }
__device__ inline float hi16(u32 q) { return __uint_as_float(q & 0xffff0000u); }
__device__ inline float2 ntload2(const float* p) {
    double d = __builtin_nontemporal_load((const double*)p);
    return *(float2*)&d;
}
__device__ inline void ntstore2(float* p, float2 v) {
    __builtin_nontemporal_store(*(double*)&v, (double*)p);
}

// ---------------- hist (edges) + weight-fold (W2c = fc2W@c1W) dual-role ----
__global__ __launch_bounds__(256) void k_hist_foldw(
    const int* __restrict__ dst, int* __restrict__ cnt,
    const float* __restrict__ fc2W, const float* __restrict__ b2,
    const float* __restrict__ c1W, float* __restrict__ W2c,
    float* __restrict__ b2c) {
    if (blockIdx.x < HIST_BLOCKS) {
        int e = blockIdx.x * 256 + threadIdx.x;
        if (e < NE) atomicAdd(&cnt[dst[e]], 1);
    } else {
        int j = (blockIdx.x - HIST_BLOCKS) * 4 + (threadIdx.x >> 6);
        int c = threadIdx.x & 63;
        if (j < 32) {
            float s = 0.f;
            for (int k = 0; k < 64; ++k) s = fmaf(fc2W[j * 64 + k], c1W[k * 64 + c], s);
            W2c[j * 64 + c] = s;
        } else if (j == 32) {
            float s = 0.f;
            for (int k = 0; k < 64; ++k) s = fmaf(b2[k], c1W[k * 64 + c], s);
            b2c[c] = s;
        }
    }
}

// single-block scan: rowptr[i+1]=sum(cnt[0..i]); + disq, cnt zero, plane pad rows
__global__ __launch_bounds__(1024) void k_scan(int* __restrict__ cnt,
                                               int* __restrict__ rowptr,
                                               float* __restrict__ disq,
                                               u16* __restrict__ Hb) {
    __shared__ int wsum[16];
    __shared__ int carry;
    int t = threadIdx.x, wave = t >> 6, lane = t & 63;
    if (t == 0) { carry = 0; rowptr[0] = 0; }
    if (t < 32) Hb[(size_t)NN * 32 + t] = 0;                 // plane0 zero row
    else if (t < 64) Hb[PLANE + (size_t)NN * 32 + (t - 32)] = 0;  // plane1
    __syncthreads();
    for (int base = 0; base < NN; base += 1024) {
        int i = base + t;
        int x = (i < NN) ? cnt[i] : 0;
        if (i < NN) {
            cnt[i] = 0;  // reset for fill cursor
            disq[i] = rsqrtf((float)x + 1.0f);  // +1 self-loop
        }
        for (int off = 1; off < 64; off <<= 1) {
            int y = __shfl_up(x, off, 64);
            if (lane >= off) x += y;
        }
        if (lane == 63) wsum[wave] = x;
        __syncthreads();
        if (wave == 0 && lane < 16) {
            int w = wsum[lane];
            for (int off = 1; off < 16; off <<= 1) {
                int y = __shfl_up(w, off, 16);
                if (lane >= off) w += y;
            }
            wsum[lane] = w;
        }
        __syncthreads();
        int incl = carry + ((wave > 0) ? wsum[wave - 1] : 0) + x;
        if (i < NN) rowptr[i + 1] = incl;
        __syncthreads();
        if (t == 1023) carry = incl;
        __syncthreads();
    }
}

// ---------------- dual-role (R9 mapping): fill blocks first, fc blocks last --
__global__ __launch_bounds__(256) void k_fill_fc(
    const int* __restrict__ src, const int* __restrict__ dst,
    const int* __restrict__ rowptr, int* __restrict__ cur,
    u16* __restrict__ esrc,
    const float* __restrict__ nf,
    const float* __restrict__ W1, const float* __restrict__ b1,
    const float* __restrict__ W2c, const float* __restrict__ b2c,
    const float* __restrict__ disq, u16* __restrict__ Hb) {
    if (blockIdx.x < FILL_BLOCKS) {
        int e = blockIdx.x * 256 + threadIdx.x;
        if (e < NE) {
            int d = dst[e];
            int pos = rowptr[d] + atomicAdd(&cur[d], 1);
            esrc[pos] = (u16)src[e];
        }
        return;
    }
    int lane = threadIdx.x & 63;
    int c = lane & 31, h = lane >> 5;
    int wid = ((blockIdx.x - FILL_BLOCKS) * 256 + threadIdx.x) >> 6;
    int nwaves = (FC_BLOCKS * 256) >> 6;
    float w1[64], w2[32];
    #pragma unroll
    for (int j = 0; j < 64; ++j) w1[j] = W1[(h * 64 + j) * 32 + c];
    #pragma unroll
    for (int j = 0; j < 32; ++j) w2[j] = W2c[j * 64 + lane];
    float b1c = b1[c], b2l = b2c[lane];
    int pl = lane >> 5, cc = lane & 31;
    for (int n = wid; n < NN; n += nwaves) {
        float x0 = __builtin_nontemporal_load(nf + (size_t)n * 128 + lane);
        float x1 = __builtin_nontemporal_load(nf + (size_t)n * 128 + 64 + lane);
        float s = 0.f;
        #pragma unroll
        for (int j = 0; j < 64; ++j) {
            float xa = rlf(x0, j), xb = rlf(x1, j);
            s = fmaf(h ? xb : xa, w1[j], s);
        }
        s += __shfl_xor(s, 32, 64);           // combine k-halves
        float hv = fmaxf(s + b1c, 0.f);       // lane l holds h1[l&31]
        float o = b2l;
        #pragma unroll
        for (int j = 0; j < 32; ++j) o = fmaf(rlf(hv, j), w2[j], o);
        Hb[(size_t)pl * PLANE + (size_t)n * 32 + cc] = f2bf(disq[n] * o);
    }
}

// ---------------- conv GEMM: planes[n] = bf16( disq[n] * (X[n] @ W) ) ------
__global__ __launch_bounds__(256) void k_gemm64(
    const float* __restrict__ X, const float* __restrict__ W,
    const float* __restrict__ disq, u16* __restrict__ Hb) {
    int lane = threadIdx.x & 63;
    int wid = (blockIdx.x * 256 + threadIdx.x) >> 6;
    int nwaves = (gridDim.x * 256) >> 6;
    float wcol[64];
    #pragma unroll
    for (int k = 0; k < 64; ++k) wcol[k] = W[k * 64 + lane];
    int pl = lane >> 5, cc = lane & 31;
    for (int n = wid; n < NN; n += nwaves) {
        float xv = __builtin_nontemporal_load(X + (size_t)n * 64 + lane);
        float acc = 0.f;
        #pragma unroll
        for (int k = 0; k < 64; ++k) acc = fmaf(rlf(xv, k), wcol[k], acc);
        Hb[(size_t)pl * PLANE + (size_t)n * 32 + cc] = f2bf(disq[n] * acc);
    }
}

// 4-row gather: quarter-wave q handles row (J+q); lane covers 2 plane channels
#define GRP(J)                                                   \
    {                                                            \
        int s = bperm(idx, (J) + q);                             \
        u32 v = *(const u32*)(Hp + (((size_t)s) << 5) + cp);     \
        a0 += lo16(v);                                           \
        a1 += hi16(v);                                           \
    }

// ---------------- CSR conv over one 32-ch plane; plane0 blocks then plane1 --
__global__ __launch_bounds__(256) void k_csr_plane(
    const u16* __restrict__ Hb, const int* __restrict__ rowptr,
    const u16* __restrict__ esrc, const float* __restrict__ disq,
    const float* __restrict__ b, const float* __restrict__ res,
    float* __restrict__ out, int do_lrelu) {
    int lane = threadIdx.x & 63;
    int q = lane >> 4;
    int cp = (lane & 15) * 2;  // channel pair within plane
    int wid = (blockIdx.x * 256 + threadIdx.x) >> 6;
    if (wid >= 2 * NN) return;
    int plane = (wid >= NN);
    int n = plane ? wid - NN : wid;
    const u16* Hp = Hb + (size_t)plane * PLANE;
    int cb = plane * 32;
    int beg = rowptr[n], end = rowptr[n + 1];
    float a0 = 0.f, a1 = 0.f;
    for (int base = beg; base < end; base += 64) {
        int cnt64 = min(64, end - base);
        int idx = (lane < cnt64) ? (int)esrc[base + lane] : NN;  // NN = zero row
        int j = 0;
        for (; j + 16 <= cnt64; j += 16) { GRP(j) GRP(j + 4) GRP(j + 8) GRP(j + 12) }
        for (; j < cnt64; j += 4) { GRP(j) }
    }
    a0 += __shfl_xor(a0, 16, 64); a0 += __shfl_xor(a0, 32, 64);
    a1 += __shfl_xor(a1, 16, 64); a1 += __shfl_xor(a1, 32, 64);
    if (q == 0) {
        u32 sv = *(const u32*)(Hp + (((size_t)n) << 5) + cp);  // self-loop
        a0 += lo16(sv);
        a1 += hi16(sv);
        float dn = disq[n];
        float v0 = dn * a0 + b[cb + cp];
        float v1 = dn * a1 + b[cb + cp + 1];
        if (do_lrelu) {
            v0 = (v0 >= 0.f) ? v0 : 0.2f * v0;
            v1 = (v1 >= 0.f) ? v1 : 0.2f * v1;
        }
        if (res) {
            float2 r = ntload2(res + (size_t)n * 64 + cb + cp);
            v0 += r.x;
            v1 += r.y;
        }
        float2 o;
        o.x = v0;
        o.y = v1;
        ntstore2(out + (size_t)n * 64 + cb + cp, o);
    }
}

// ---------------- final 64->2 projection: out = X @ FW + fb ----------------
__global__ __launch_bounds__(256) void k_final(
    const float* __restrict__ X, const float* __restrict__ FW,
    const float* __restrict__ fb, float* __restrict__ out) {
    int lane = threadIdx.x & 63;
    int n = (blockIdx.x * 256 + threadIdx.x) >> 6;
    if (n >= NN) return;
    float v = __builtin_nontemporal_load(X + (size_t)n * 64 + lane);
    float p0 = v * FW[lane * 2 + 0];
    float p1 = v * FW[lane * 2 + 1];
    for (int off = 32; off; off >>= 1) {
        p0 += __shfl_xor(p0, off, 64);
        p1 += __shfl_xor(p1, off, 64);
    }
    if (lane == 0) {
        out[n * 2 + 0] = p0 + fb[0];
        out[n * 2 + 1] = p1 + fb[1];
    }
}

extern "C" void kernel_launch(void* const* d_in, const int* in_sizes, int n_in,
                              void* d_out, int out_size, void* d_ws, size_t ws_size,
                              hipStream_t stream) {
    const float* nf   = (const float*)d_in[0];
    const int*   ei   = (const int*)d_in[1];
    const float* fc1W = (const float*)d_in[2];
    const float* fc1b = (const float*)d_in[3];
    const float* fc2W = (const float*)d_in[4];
    const float* fc2b = (const float*)d_in[5];
    const float* cW[4] = {(const float*)d_in[6], (const float*)d_in[8],
                          (const float*)d_in[10], (const float*)d_in[12]};
    const float* cb[4] = {(const float*)d_in[7], (const float*)d_in[9],
                          (const float*)d_in[11], (const float*)d_in[13]};
    const float* fW = (const float*)d_in[14];
    const float* fb = (const float*)d_in[15];
    const int* src = ei;
    const int* dst = ei + NE;

    float* ws     = (float*)d_ws;
    float* disq   = ws;                          // 50048 f
    int*   cnt    = (int*)(ws + 50048);          // 50048 i (histogram, then cursor)
    int*   rowptr = cnt + 50048;                 // 50056 i
    u16*   esrc   = (u16*)(rowptr + 50056);      // 800000 u16
    float* W2c    = (float*)(esrc + 800000);     // 2048 f
    float* b2c    = W2c + 2048;                  // 64 f
    float* B0     = b2c + 64;                    // NN*64 f
    float* B1     = B0 + (size_t)NN * 64;        // NN*64 f
    u16*   Hb     = (u16*)(B1 + (size_t)NN * 64);// 2 planes of (NN+1)*32 u16

    // ---- CSR build + weight fold + fc (R9-proven overlap) ----
    hipMemsetAsync(cnt, 0, 50048 * sizeof(int), stream);
    k_hist_foldw<<<HIST_BLOCKS + 9, 256, 0, stream>>>(dst, cnt, fc2W, fc2b, cW[0],
                                                      W2c, b2c);
    k_scan<<<1, 1024, 0, stream>>>(cnt, rowptr, disq, Hb);
    k_fill_fc<<<FILL_BLOCKS + FC_BLOCKS, 256, 0, stream>>>(
        src, dst, rowptr, cnt, esrc, nf, fc1W, fc1b, W2c, b2c, disq, Hb);

    const int cgrid = (2 * NN * 64) / 256;  // one wave per (node, plane)

    // conv1: out1 -> B1
    k_csr_plane<<<cgrid, 256, 0, stream>>>(Hb, rowptr, esrc, disq, cb[0], nullptr, B1, 1);
    // conv2: out2 = lrelu(conv)+out1 -> B0
    k_gemm64<<<1024, 256, 0, stream>>>(B1, cW[1], disq, Hb);
    k_csr_plane<<<cgrid, 256, 0, stream>>>(Hb, rowptr, esrc, disq, cb[1], B1, B0, 1);
    // conv3: out3 -> B1
    k_gemm64<<<1024, 256, 0, stream>>>(B0, cW[2], disq, Hb);
    k_csr_plane<<<cgrid, 256, 0, stream>>>(Hb, rowptr, esrc, disq, cb[2], nullptr, B1, 1);
    // conv4: out4 = conv+out2 -> B0 (in-place over res), then project
    k_gemm64<<<1024, 256, 0, stream>>>(B1, cW[3], disq, Hb);
    k_csr_plane<<<cgrid, 256, 0, stream>>>(Hb, rowptr, esrc, disq, cb[3], B0, B0, 0);
    k_final<<<(NN * 64) / 256, 256, 0, stream>>>(B0, fW, fb, (float*)d_out);
}

// Round 12
// 414.184 us; speedup vs baseline: 1.0495x; 1.0495x over previous
//
#include <hip/hip_runtime.h>

#define NN 50000
#define NE 800000
#define HIST_BLOCKS ((NE + 255) / 256)   // 3125
#define FILL_BLOCKS HIST_BLOCKS          // 3125
#define FC_BLOCKS 1024
#define PLANE ((NN + 1) * 32)            // u16 elems per channel-plane (row NN = zeros)

typedef unsigned short u16;
typedef unsigned int u32;

__device__ inline float rlf(float v, int l) {
    return __int_as_float(__builtin_amdgcn_readlane(__float_as_int(v), l));
}
__device__ inline u16 f2bf(float f) {  // round-to-nearest-even
    u32 u = __float_as_uint(f);
    u32 r = (u + 0x7FFFu + ((u >> 16) & 1u)) >> 16;
    return (u16)r;
}
__device__ inline float lo16(u32 q) { return __uint_as_float(q << 16); }
__device__ inline float hi16(u32 q) { return __uint_as_float(q & 0xffff0000u); }

// ---------------- hist (edges) + weight-fold (W2c = fc2W@c1W) dual-role ----
__global__ __launch_bounds__(256) void k_hist_foldw(
    const int* __restrict__ dst, int* __restrict__ cnt,
    const float* __restrict__ fc2W, const float* __restrict__ b2,
    const float* __restrict__ c1W, float* __restrict__ W2c,
    float* __restrict__ b2c) {
    if (blockIdx.x < HIST_BLOCKS) {
        int e = blockIdx.x * 256 + threadIdx.x;
        if (e < NE) atomicAdd(&cnt[dst[e]], 1);
    } else {
        int j = (blockIdx.x - HIST_BLOCKS) * 4 + (threadIdx.x >> 6);
        int c = threadIdx.x & 63;
        if (j < 32) {
            float s = 0.f;
            for (int k = 0; k < 64; ++k) s = fmaf(fc2W[j * 64 + k], c1W[k * 64 + c], s);
            W2c[j * 64 + c] = s;
        } else if (j == 32) {
            float s = 0.f;
            for (int k = 0; k < 64; ++k) s = fmaf(b2[k], c1W[k * 64 + c], s);
            b2c[c] = s;
        }
    }
}

// single-block scan: rowptr[i+1]=sum(cnt[0..i]); + disq, cnt zero, plane pad rows
__global__ __launch_bounds__(1024) void k_scan(int* __restrict__ cnt,
                                               int* __restrict__ rowptr,
                                               float* __restrict__ disq,
                                               u16* __restrict__ Hb) {
    __shared__ int wsum[16];
    __shared__ int carry;
    int t = threadIdx.x, wave = t >> 6, lane = t & 63;
    if (t == 0) { carry = 0; rowptr[0] = 0; }
    if (t < 32) Hb[(size_t)NN * 32 + t] = 0;                      // plane0 zero row
    else if (t < 64) Hb[PLANE + (size_t)NN * 32 + (t - 32)] = 0;  // plane1
    __syncthreads();
    for (int base = 0; base < NN; base += 1024) {
        int i = base + t;
        int x = (i < NN) ? cnt[i] : 0;
        if (i < NN) {
            cnt[i] = 0;  // reset for fill cursor
            disq[i] = rsqrtf((float)x + 1.0f);  // +1 self-loop
        }
        for (int off = 1; off < 64; off <<= 1) {
            int y = __shfl_up(x, off, 64);
            if (lane >= off) x += y;
        }
        if (lane == 63) wsum[wave] = x;
        __syncthreads();
        if (wave == 0 && lane < 16) {
            int w = wsum[lane];
            for (int off = 1; off < 16; off <<= 1) {
                int y = __shfl_up(w, off, 16);
                if (lane >= off) w += y;
            }
            wsum[lane] = w;
        }
        __syncthreads();
        int incl = carry + ((wave > 0) ? wsum[wave - 1] : 0) + x;
        if (i < NN) rowptr[i + 1] = incl;
        __syncthreads();
        if (t == 1023) carry = incl;
        __syncthreads();
    }
}

// ---------------- dual-role (R9 mapping): fill blocks first, fc blocks last --
__global__ __launch_bounds__(256) void k_fill_fc(
    const int* __restrict__ src, const int* __restrict__ dst,
    const int* __restrict__ rowptr, int* __restrict__ cur,
    u16* __restrict__ esrc,
    const float* __restrict__ nf,
    const float* __restrict__ W1, const float* __restrict__ b1,
    const float* __restrict__ W2c, const float* __restrict__ b2c,
    const float* __restrict__ disq, u16* __restrict__ Hb) {
    if (blockIdx.x < FILL_BLOCKS) {
        int e = blockIdx.x * 256 + threadIdx.x;
        if (e < NE) {
            int d = dst[e];
            int pos = rowptr[d] + atomicAdd(&cur[d], 1);
            esrc[pos] = (u16)src[e];
        }
        return;
    }
    int lane = threadIdx.x & 63;
    int c = lane & 31, h = lane >> 5;
    int wid = ((blockIdx.x - FILL_BLOCKS) * 256 + threadIdx.x) >> 6;
    int nwaves = (FC_BLOCKS * 256) >> 6;
    float w1[64], w2[32];
    #pragma unroll
    for (int j = 0; j < 64; ++j) w1[j] = W1[(h * 64 + j) * 32 + c];
    #pragma unroll
    for (int j = 0; j < 32; ++j) w2[j] = W2c[j * 64 + lane];
    float b1c = b1[c], b2l = b2c[lane];
    int pl = lane >> 5, cc = lane & 31;
    for (int n = wid; n < NN; n += nwaves) {
        float x0 = nf[(size_t)n * 128 + lane];
        float x1 = nf[(size_t)n * 128 + 64 + lane];
        float s = 0.f;
        #pragma unroll
        for (int j = 0; j < 64; ++j) {
            float xa = rlf(x0, j), xb = rlf(x1, j);
            s = fmaf(h ? xb : xa, w1[j], s);
        }
        s += __shfl_xor(s, 32, 64);           // combine k-halves
        float hv = fmaxf(s + b1c, 0.f);       // lane l holds h1[l&31]
        float o = b2l;
        #pragma unroll
        for (int j = 0; j < 32; ++j) o = fmaf(rlf(hv, j), w2[j], o);
        Hb[(size_t)pl * PLANE + (size_t)n * 32 + cc] = f2bf(disq[n] * o);
    }
}

// ---------------- conv GEMM: planes[n] = bf16( disq[n] * (X[n] @ W) ) ------
__global__ __launch_bounds__(256) void k_gemm64(
    const float* __restrict__ X, const float* __restrict__ W,
    const float* __restrict__ disq, u16* __restrict__ Hb) {
    int lane = threadIdx.x & 63;
    int wid = (blockIdx.x * 256 + threadIdx.x) >> 6;
    int nwaves = (gridDim.x * 256) >> 6;
    float wcol[64];
    #pragma unroll
    for (int k = 0; k < 64; ++k) wcol[k] = W[k * 64 + lane];
    int pl = lane >> 5, cc = lane & 31;
    for (int n = wid; n < NN; n += nwaves) {
        float xv = X[(size_t)n * 64 + lane];
        float acc = 0.f;
        #pragma unroll
        for (int k = 0; k < 64; ++k) acc = fmaf(rlf(xv, k), wcol[k], acc);
        Hb[(size_t)pl * PLANE + (size_t)n * 32 + cc] = f2bf(disq[n] * acc);
    }
}

// 4-row gather: quarter-wave q handles row (J+q); lane covers 2 plane channels
// index select via readlane + cndmask chain (pure VALU, no LDS)
#define GRP(J)                                                              \
    {                                                                       \
        int p0 = __builtin_amdgcn_readlane(idx, (J) + 0);                   \
        int p1 = __builtin_amdgcn_readlane(idx, (J) + 1);                   \
        int p2 = __builtin_amdgcn_readlane(idx, (J) + 2);                   \
        int p3 = __builtin_amdgcn_readlane(idx, (J) + 3);                   \
        int s = (q == 0) ? p0 : ((q == 1) ? p1 : ((q == 2) ? p2 : p3));     \
        u32 v = *(const u32*)(Hp + (((size_t)s) << 5) + cp);                \
        a0 += lo16(v);                                                      \
        a1 += hi16(v);                                                      \
    }

// ---------------- CSR conv over one 32-ch plane; plane0 waves then plane1 --
__global__ __launch_bounds__(256) void k_csr_plane(
    const u16* __restrict__ Hb, const int* __restrict__ rowptr,
    const u16* __restrict__ esrc, const float* __restrict__ disq,
    const float* __restrict__ b, const float* __restrict__ res,
    float* __restrict__ out, int do_lrelu) {
    int lane = threadIdx.x & 63;
    int q = lane >> 4;
    int cp = (lane & 15) * 2;  // channel pair within plane
    int wid = (blockIdx.x * 256 + threadIdx.x) >> 6;
    if (wid >= 2 * NN) return;
    int plane = (wid >= NN);
    int n = plane ? wid - NN : wid;
    const u16* Hp = Hb + (size_t)plane * PLANE;
    int cb = plane * 32;
    int beg = rowptr[n], end = rowptr[n + 1];
    float a0 = 0.f, a1 = 0.f;
    for (int base = beg; base < end; base += 64) {
        int cnt64 = min(64, end - base);
        int idx = (lane < cnt64) ? (int)esrc[base + lane] : NN;  // NN = zero row
        int j = 0;
        for (; j + 16 <= cnt64; j += 16) { GRP(j) GRP(j + 4) GRP(j + 8) GRP(j + 12) }
        for (; j < cnt64; j += 4) { GRP(j) }
    }
    a0 += __shfl_xor(a0, 16, 64); a0 += __shfl_xor(a0, 32, 64);
    a1 += __shfl_xor(a1, 16, 64); a1 += __shfl_xor(a1, 32, 64);
    if (q == 0) {
        u32 sv = *(const u32*)(Hp + (((size_t)n) << 5) + cp);  // self-loop
        a0 += lo16(sv);
        a1 += hi16(sv);
        float dn = disq[n];
        float v0 = dn * a0 + b[cb + cp];
        float v1 = dn * a1 + b[cb + cp + 1];
        if (do_lrelu) {
            v0 = (v0 >= 0.f) ? v0 : 0.2f * v0;
            v1 = (v1 >= 0.f) ? v1 : 0.2f * v1;
        }
        if (res) {
            float2 r = *(const float2*)(res + (size_t)n * 64 + cb + cp);
            v0 += r.x;
            v1 += r.y;
        }
        float2 o;
        o.x = v0;
        o.y = v1;
        *(float2*)(out + (size_t)n * 64 + cb + cp) = o;
    }
}

// ---------------- final 64->2 projection: out = X @ FW + fb ----------------
__global__ __launch_bounds__(256) void k_final(
    const float* __restrict__ X, const float* __restrict__ FW,
    const float* __restrict__ fb, float* __restrict__ out) {
    int lane = threadIdx.x & 63;
    int n = (blockIdx.x * 256 + threadIdx.x) >> 6;
    if (n >= NN) return;
    float v = X[(size_t)n * 64 + lane];
    float p0 = v * FW[lane * 2 + 0];
    float p1 = v * FW[lane * 2 + 1];
    for (int off = 32; off; off >>= 1) {
        p0 += __shfl_xor(p0, off, 64);
        p1 += __shfl_xor(p1, off, 64);
    }
    if (lane == 0) {
        out[n * 2 + 0] = p0 + fb[0];
        out[n * 2 + 1] = p1 + fb[1];
    }
}

extern "C" void kernel_launch(void* const* d_in, const int* in_sizes, int n_in,
                              void* d_out, int out_size, void* d_ws, size_t ws_size,
                              hipStream_t stream) {
    const float* nf   = (const float*)d_in[0];
    const int*   ei   = (const int*)d_in[1];
    const float* fc1W = (const float*)d_in[2];
    const float* fc1b = (const float*)d_in[3];
    const float* fc2W = (const float*)d_in[4];
    const float* fc2b = (const float*)d_in[5];
    const float* cW[4] = {(const float*)d_in[6], (const float*)d_in[8],
                          (const float*)d_in[10], (const float*)d_in[12]};
    const float* cb[4] = {(const float*)d_in[7], (const float*)d_in[9],
                          (const float*)d_in[11], (const float*)d_in[13]};
    const float* fW = (const float*)d_in[14];
    const float* fb = (const float*)d_in[15];
    const int* src = ei;
    const int* dst = ei + NE;

    float* ws     = (float*)d_ws;
    float* disq   = ws;                          // 50048 f
    int*   cnt    = (int*)(ws + 50048);          // 50048 i (histogram, then cursor)
    int*   rowptr = cnt + 50048;                 // 50056 i
    u16*   esrc   = (u16*)(rowptr + 50056);      // 800000 u16
    float* W2c    = (float*)(esrc + 800000);     // 2048 f
    float* b2c    = W2c + 2048;                  // 64 f
    float* B0     = b2c + 64;                    // NN*64 f
    float* B1     = B0 + (size_t)NN * 64;        // NN*64 f
    u16*   Hb     = (u16*)(B1 + (size_t)NN * 64);// 2 planes of (NN+1)*32 u16

    // ---- CSR build + weight fold + fc (R9-proven overlap) ----
    hipMemsetAsync(cnt, 0, 50048 * sizeof(int), stream);
    k_hist_foldw<<<HIST_BLOCKS + 9, 256, 0, stream>>>(dst, cnt, fc2W, fc2b, cW[0],
                                                      W2c, b2c);
    k_scan<<<1, 1024, 0, stream>>>(cnt, rowptr, disq, Hb);
    k_fill_fc<<<FILL_BLOCKS + FC_BLOCKS, 256, 0, stream>>>(
        src, dst, rowptr, cnt, esrc, nf, fc1W, fc1b, W2c, b2c, disq, Hb);

    const int cgrid = (2 * NN * 64) / 256;  // one wave per (node, plane)

    // conv1: out1 -> B1
    k_csr_plane<<<cgrid, 256, 0, stream>>>(Hb, rowptr, esrc, disq, cb[0], nullptr, B1, 1);
    // conv2: out2 = lrelu(conv)+out1 -> B0
    k_gemm64<<<1024, 256, 0, stream>>>(B1, cW[1], disq, Hb);
    k_csr_plane<<<cgrid, 256, 0, stream>>>(Hb, rowptr, esrc, disq, cb[1], B1, B0, 1);
    // conv3: out3 -> B1
    k_gemm64<<<1024, 256, 0, stream>>>(B0, cW[2], disq, Hb);
    k_csr_plane<<<cgrid, 256, 0, stream>>>(Hb, rowptr, esrc, disq, cb[2], nullptr, B1, 1);
    // conv4: out4 = conv+out2 -> B0 (in-place over res), then project
    k_gemm64<<<1024, 256, 0, stream>>>(B1, cW[3], disq, Hb);
    k_csr_plane<<<cgrid, 256, 0, stream>>>(Hb, rowptr, esrc, disq, cb[3], B0, B0, 0);
    k_final<<<(NN * 64) / 256, 256, 0, stream>>>(B0, fW, fb, (float*)d_out);
}

// Round 13
// 314.562 us; speedup vs baseline: 1.3818x; 1.3167x over previous
//
#include <hip/hip_runtime.h>

#define NN 50000
#define NHALF 25000
#define NE 800000
#define HIST_BLOCKS ((NE + 255) / 256)   // 3125
#define FILL_BLOCKS HIST_BLOCKS          // 3125
#define FC_BLOCKS 1024

typedef unsigned short u16;
typedef unsigned int u32;

__device__ inline float rlf(float v, int l) {
    return __int_as_float(__builtin_amdgcn_readlane(__float_as_int(v), l));
}
__device__ inline u16 f2bf(float f) {  // round-to-nearest-even
    u32 u = __float_as_uint(f);
    u32 r = (u + 0x7FFFu + ((u >> 16) & 1u)) >> 16;
    return (u16)r;
}
__device__ inline float lo16(u32 q) { return __uint_as_float(q << 16); }
__device__ inline float hi16(u32 q) { return __uint_as_float(q & 0xffff0000u); }

// ---------------- hist (edges) + weight-fold (W2c = fc2W@c1W) dual-role ----
__global__ __launch_bounds__(256) void k_hist_foldw(
    const int* __restrict__ dst, int* __restrict__ cnt,
    const float* __restrict__ fc2W, const float* __restrict__ b2,
    const float* __restrict__ c1W, float* __restrict__ W2c,
    float* __restrict__ b2c) {
    if (blockIdx.x < HIST_BLOCKS) {
        int e = blockIdx.x * 256 + threadIdx.x;
        if (e < NE) atomicAdd(&cnt[dst[e]], 1);
    } else {
        int j = (blockIdx.x - HIST_BLOCKS) * 4 + (threadIdx.x >> 6);
        int c = threadIdx.x & 63;
        if (j < 32) {
            float s = 0.f;
            for (int k = 0; k < 64; ++k) s = fmaf(fc2W[j * 64 + k], c1W[k * 64 + c], s);
            W2c[j * 64 + c] = s;
        } else if (j == 32) {
            float s = 0.f;
            for (int k = 0; k < 64; ++k) s = fmaf(b2[k], c1W[k * 64 + c], s);
            b2c[c] = s;
        }
    }
}

// single-block scan: rowptr[i+1]=sum(cnt[0..i]); + disq, cnt zero, Hb pad row
__global__ __launch_bounds__(1024) void k_scan(int* __restrict__ cnt,
                                               int* __restrict__ rowptr,
                                               float* __restrict__ disq,
                                               u16* __restrict__ Hb) {
    __shared__ int wsum[16];
    __shared__ int carry;
    int t = threadIdx.x, wave = t >> 6, lane = t & 63;
    if (t == 0) { carry = 0; rowptr[0] = 0; }
    if (t < 64) Hb[(size_t)NN * 64 + t] = 0;  // zero pad-row for gather tails
    __syncthreads();
    for (int base = 0; base < NN; base += 1024) {
        int i = base + t;
        int x = (i < NN) ? cnt[i] : 0;
        if (i < NN) {
            cnt[i] = 0;  // reset for fill cursor
            disq[i] = rsqrtf((float)x + 1.0f);  // +1 self-loop
        }
        for (int off = 1; off < 64; off <<= 1) {
            int y = __shfl_up(x, off, 64);
            if (lane >= off) x += y;
        }
        if (lane == 63) wsum[wave] = x;
        __syncthreads();
        if (wave == 0 && lane < 16) {
            int w = wsum[lane];
            for (int off = 1; off < 16; off <<= 1) {
                int y = __shfl_up(w, off, 16);
                if (lane >= off) w += y;
            }
            wsum[lane] = w;
        }
        __syncthreads();
        int incl = carry + ((wave > 0) ? wsum[wave - 1] : 0) + x;
        if (i < NN) rowptr[i + 1] = incl;
        __syncthreads();
        if (t == 1023) carry = incl;
        __syncthreads();
    }
}

// ---------------- dual-role, LPT order: fc blocks FIRST, fill backfills -----
__global__ __launch_bounds__(256) void k_fill_fc(
    const int* __restrict__ src, const int* __restrict__ dst,
    const int* __restrict__ rowptr, int* __restrict__ cur,
    u16* __restrict__ esrc,
    const float* __restrict__ nf,
    const float* __restrict__ W1, const float* __restrict__ b1,
    const float* __restrict__ W2c, const float* __restrict__ b2c,
    const float* __restrict__ disq, u16* __restrict__ Hb) {
    if (blockIdx.x >= FC_BLOCKS) {  // fill role
        int e = (blockIdx.x - FC_BLOCKS) * 256 + threadIdx.x;
        if (e < NE) {
            int d = dst[e];
            int pos = rowptr[d] + atomicAdd(&cur[d], 1);
            esrc[pos] = (u16)src[e];
        }
        return;
    }
    int lane = threadIdx.x & 63;
    int c = lane & 31, h = lane >> 5;
    int wid = (blockIdx.x * 256 + threadIdx.x) >> 6;
    int nwaves = (FC_BLOCKS * 256) >> 6;
    float w1[64], w2[32];
    #pragma unroll
    for (int j = 0; j < 64; ++j) w1[j] = W1[(h * 64 + j) * 32 + c];
    #pragma unroll
    for (int j = 0; j < 32; ++j) w2[j] = W2c[j * 64 + lane];
    float b1c = b1[c], b2l = b2c[lane];
    for (int n = wid; n < NN; n += nwaves) {
        float x0 = nf[(size_t)n * 128 + lane];
        float x1 = nf[(size_t)n * 128 + 64 + lane];
        float s = 0.f;
        #pragma unroll
        for (int j = 0; j < 64; ++j) {
            float xa = rlf(x0, j), xb = rlf(x1, j);
            s = fmaf(h ? xb : xa, w1[j], s);
        }
        s += __shfl_xor(s, 32, 64);           // combine k-halves
        float hv = fmaxf(s + b1c, 0.f);       // lane l holds h1[l&31]
        float o = b2l;
        #pragma unroll
        for (int j = 0; j < 32; ++j) o = fmaf(rlf(hv, j), w2[j], o);
        Hb[(size_t)n * 64 + lane] = f2bf(disq[n] * o);
    }
}

// ---------------- conv GEMM: Hb[n] = bf16( disq[n] * (X[n] @ W) ) ----------
__global__ __launch_bounds__(256) void k_gemm64(
    const float* __restrict__ X, const float* __restrict__ W,
    const float* __restrict__ disq, u16* __restrict__ Hb) {
    int lane = threadIdx.x & 63;
    int wid = (blockIdx.x * 256 + threadIdx.x) >> 6;
    int nwaves = (gridDim.x * 256) >> 6;
    float wcol[64];
    #pragma unroll
    for (int k = 0; k < 64; ++k) wcol[k] = W[k * 64 + lane];
    for (int n = wid; n < NN; n += nwaves) {
        float xv = X[(size_t)n * 64 + lane];
        float acc = 0.f;
        #pragma unroll
        for (int k = 0; k < 64; ++k) acc = fmaf(rlf(xv, k), wcol[k], acc);
        Hb[(size_t)n * 64 + lane] = f2bf(disq[n] * acc);
    }
}

// 4-row gather for chain A/B: quarter-wave q takes row (J+q); lane = 4 channels
#define GRPA(J)                                                             \
    {                                                                       \
        int p0 = __builtin_amdgcn_readlane(idx1, (J) + 0);                  \
        int p1 = __builtin_amdgcn_readlane(idx1, (J) + 1);                  \
        int p2 = __builtin_amdgcn_readlane(idx1, (J) + 2);                  \
        int p3 = __builtin_amdgcn_readlane(idx1, (J) + 3);                  \
        int s = (q == 0) ? p0 : ((q == 1) ? p1 : ((q == 2) ? p2 : p3));     \
        uint2 v = *(const uint2*)(Hb + (((size_t)s) << 6) + c4);            \
        a0 += lo16(v.x); a1 += hi16(v.x); a2 += lo16(v.y); a3 += hi16(v.y); \
    }
#define GRPB(J)                                                             \
    {                                                                       \
        int p0 = __builtin_amdgcn_readlane(idx2, (J) + 0);                  \
        int p1 = __builtin_amdgcn_readlane(idx2, (J) + 1);                  \
        int p2 = __builtin_amdgcn_readlane(idx2, (J) + 2);                  \
        int p3 = __builtin_amdgcn_readlane(idx2, (J) + 3);                  \
        int s = (q == 0) ? p0 : ((q == 1) ? p1 : ((q == 2) ? p2 : p3));     \
        uint2 v = *(const uint2*)(Hb + (((size_t)s) << 6) + c4);            \
        g0 += lo16(v.x); g1 += hi16(v.x); g2 += lo16(v.y); g3 += hi16(v.y); \
    }

// ---------------- CSR conv: 2 nodes per wave (w, w+NHALF), dual chains ------
__global__ __launch_bounds__(256) void k_csr_conv(
    const u16* __restrict__ Hb, const int* __restrict__ rowptr,
    const u16* __restrict__ esrc, const float* __restrict__ disq,
    const float* __restrict__ b, const float* __restrict__ res,
    float* __restrict__ out, int do_lrelu) {
    int lane = threadIdx.x & 63;
    int q = lane >> 4;
    int c4 = (lane & 15) * 4;
    int w = (blockIdx.x * 256 + threadIdx.x) >> 6;
    if (w >= NHALF) return;
    int n1 = w, n2 = w + NHALF;
    int base1 = rowptr[n1], end1 = rowptr[n1 + 1];
    int base2 = rowptr[n2], end2 = rowptr[n2 + 1];
    float a0 = 0.f, a1 = 0.f, a2 = 0.f, a3 = 0.f;
    float g0 = 0.f, g1 = 0.f, g2 = 0.f, g3 = 0.f;
    while (base1 < end1 || base2 < end2) {
        int m1 = min(max(end1 - base1, 0), 64);
        int m2 = min(max(end2 - base2, 0), 64);
        int idx1 = (lane < m1) ? (int)esrc[base1 + lane] : NN;  // NN = zero row
        int idx2 = (lane < m2) ? (int)esrc[base2 + lane] : NN;
        int m = max(m1, m2);
        int j = 0;
        for (; j + 16 <= m; j += 16) {
            GRPA(j) GRPB(j) GRPA(j + 4) GRPB(j + 4)
            GRPA(j + 8) GRPB(j + 8) GRPA(j + 12) GRPB(j + 12)
        }
        for (; j < m; j += 4) { GRPA(j) GRPB(j) }
        base1 += 64;
        base2 += 64;
    }
    // combine quarters
    a0 += __shfl_xor(a0, 16, 64); a0 += __shfl_xor(a0, 32, 64);
    a1 += __shfl_xor(a1, 16, 64); a1 += __shfl_xor(a1, 32, 64);
    a2 += __shfl_xor(a2, 16, 64); a2 += __shfl_xor(a2, 32, 64);
    a3 += __shfl_xor(a3, 16, 64); a3 += __shfl_xor(a3, 32, 64);
    g0 += __shfl_xor(g0, 16, 64); g0 += __shfl_xor(g0, 32, 64);
    g1 += __shfl_xor(g1, 16, 64); g1 += __shfl_xor(g1, 32, 64);
    g2 += __shfl_xor(g2, 16, 64); g2 += __shfl_xor(g2, 32, 64);
    g3 += __shfl_xor(g3, 16, 64); g3 += __shfl_xor(g3, 32, 64);
    if (q < 2) {
        int n = (q == 0) ? n1 : n2;
        float e0 = (q == 0) ? a0 : g0;
        float e1 = (q == 0) ? a1 : g1;
        float e2 = (q == 0) ? a2 : g2;
        float e3 = (q == 0) ? a3 : g3;
        uint2 sv = *(const uint2*)(Hb + (((size_t)n) << 6) + c4);  // self-loop
        e0 += lo16(sv.x); e1 += hi16(sv.x); e2 += lo16(sv.y); e3 += hi16(sv.y);
        float dn = disq[n];
        float4 bv = *(const float4*)(b + c4);
        float v0 = dn * e0 + bv.x;
        float v1 = dn * e1 + bv.y;
        float v2 = dn * e2 + bv.z;
        float v3 = dn * e3 + bv.w;
        if (do_lrelu) {
            v0 = (v0 >= 0.f) ? v0 : 0.2f * v0;
            v1 = (v1 >= 0.f) ? v1 : 0.2f * v1;
            v2 = (v2 >= 0.f) ? v2 : 0.2f * v2;
            v3 = (v3 >= 0.f) ? v3 : 0.2f * v3;
        }
        if (res) {
            float4 r = *(const float4*)(res + (((size_t)n) << 6) + c4);
            v0 += r.x; v1 += r.y; v2 += r.z; v3 += r.w;
        }
        float4 o;
        o.x = v0; o.y = v1; o.z = v2; o.w = v3;
        *(float4*)(out + (((size_t)n) << 6) + c4) = o;
    }
}

// ---------------- conv4 + residual + final 64->2 projection (2 nodes/wave) --
__global__ __launch_bounds__(256) void k_csr_conv_final(
    const u16* __restrict__ Hb, const int* __restrict__ rowptr,
    const u16* __restrict__ esrc, const float* __restrict__ disq,
    const float* __restrict__ b, const float* __restrict__ res,
    const float* __restrict__ FW, const float* __restrict__ fb,
    float* __restrict__ out) {
    int lane = threadIdx.x & 63;
    int q = lane >> 4;
    int c4 = (lane & 15) * 4;
    int w = (blockIdx.x * 256 + threadIdx.x) >> 6;
    if (w >= NHALF) return;
    int n1 = w, n2 = w + NHALF;
    int base1 = rowptr[n1], end1 = rowptr[n1 + 1];
    int base2 = rowptr[n2], end2 = rowptr[n2 + 1];
    float a0 = 0.f, a1 = 0.f, a2 = 0.f, a3 = 0.f;
    float g0 = 0.f, g1 = 0.f, g2 = 0.f, g3 = 0.f;
    while (base1 < end1 || base2 < end2) {
        int m1 = min(max(end1 - base1, 0), 64);
        int m2 = min(max(end2 - base2, 0), 64);
        int idx1 = (lane < m1) ? (int)esrc[base1 + lane] : NN;
        int idx2 = (lane < m2) ? (int)esrc[base2 + lane] : NN;
        int m = max(m1, m2);
        int j = 0;
        for (; j + 16 <= m; j += 16) {
            GRPA(j) GRPB(j) GRPA(j + 4) GRPB(j + 4)
            GRPA(j + 8) GRPB(j + 8) GRPA(j + 12) GRPB(j + 12)
        }
        for (; j < m; j += 4) { GRPA(j) GRPB(j) }
        base1 += 64;
        base2 += 64;
    }
    a0 += __shfl_xor(a0, 16, 64); a0 += __shfl_xor(a0, 32, 64);
    a1 += __shfl_xor(a1, 16, 64); a1 += __shfl_xor(a1, 32, 64);
    a2 += __shfl_xor(a2, 16, 64); a2 += __shfl_xor(a2, 32, 64);
    a3 += __shfl_xor(a3, 16, 64); a3 += __shfl_xor(a3, 32, 64);
    g0 += __shfl_xor(g0, 16, 64); g0 += __shfl_xor(g0, 32, 64);
    g1 += __shfl_xor(g1, 16, 64); g1 += __shfl_xor(g1, 32, 64);
    g2 += __shfl_xor(g2, 16, 64); g2 += __shfl_xor(g2, 32, 64);
    g3 += __shfl_xor(g3, 16, 64); g3 += __shfl_xor(g3, 32, 64);
    float p0 = 0.f, p1 = 0.f;
    int n = (q == 0) ? n1 : n2;
    if (q < 2) {
        float e0 = (q == 0) ? a0 : g0;
        float e1 = (q == 0) ? a1 : g1;
        float e2 = (q == 0) ? a2 : g2;
        float e3 = (q == 0) ? a3 : g3;
        uint2 sv = *(const uint2*)(Hb + (((size_t)n) << 6) + c4);
        e0 += lo16(sv.x); e1 += hi16(sv.x); e2 += lo16(sv.y); e3 += hi16(sv.y);
        float dn = disq[n];
        float4 bv = *(const float4*)(b + c4);
        float4 r = *(const float4*)(res + (((size_t)n) << 6) + c4);
        float v0 = dn * e0 + bv.x + r.x;   // out4, no lrelu
        float v1 = dn * e1 + bv.y + r.y;
        float v2 = dn * e2 + bv.z + r.z;
        float v3 = dn * e3 + bv.w + r.w;
        float4 f01 = *(const float4*)(FW + c4 * 2);
        float4 f23 = *(const float4*)(FW + c4 * 2 + 4);
        p0 = v0 * f01.x + v1 * f01.z + v2 * f23.x + v3 * f23.z;
        p1 = v0 * f01.y + v1 * f01.w + v2 * f23.y + v3 * f23.w;
    }
    for (int off = 1; off < 16; off <<= 1) {  // reduce within 16-lane quarter
        p0 += __shfl_xor(p0, off, 64);
        p1 += __shfl_xor(p1, off, 64);
    }
    if (lane == 0 || lane == 16) {
        out[n * 2 + 0] = p0 + fb[0];
        out[n * 2 + 1] = p1 + fb[1];
    }
}

extern "C" void kernel_launch(void* const* d_in, const int* in_sizes, int n_in,
                              void* d_out, int out_size, void* d_ws, size_t ws_size,
                              hipStream_t stream) {
    const float* nf   = (const float*)d_in[0];
    const int*   ei   = (const int*)d_in[1];
    const float* fc1W = (const float*)d_in[2];
    const float* fc1b = (const float*)d_in[3];
    const float* fc2W = (const float*)d_in[4];
    const float* fc2b = (const float*)d_in[5];
    const float* cW[4] = {(const float*)d_in[6], (const float*)d_in[8],
                          (const float*)d_in[10], (const float*)d_in[12]};
    const float* cb[4] = {(const float*)d_in[7], (const float*)d_in[9],
                          (const float*)d_in[11], (const float*)d_in[13]};
    const float* fW = (const float*)d_in[14];
    const float* fb = (const float*)d_in[15];
    const int* src = ei;
    const int* dst = ei + NE;

    float* ws     = (float*)d_ws;
    float* disq   = ws;                          // 50048 f
    int*   cnt    = (int*)(ws + 50048);          // 50048 i (histogram, then cursor)
    int*   rowptr = cnt + 50048;                 // 50056 i
    u16*   esrc   = (u16*)(rowptr + 50056);      // 800000 u16
    float* W2c    = (float*)(esrc + 800064);     // 2048 f
    float* b2c    = W2c + 2048;                  // 64 f
    float* B0     = b2c + 64;                    // NN*64 f
    float* B1     = B0 + (size_t)NN * 64;        // NN*64 f
    u16*   Hb     = (u16*)(B1 + (size_t)NN * 64);// (NN+1)*64 u16 (row NN = zeros)

    // ---- CSR build + weight fold + fc (LPT overlap: fc first) ----
    hipMemsetAsync(cnt, 0, 50048 * sizeof(int), stream);
    k_hist_foldw<<<HIST_BLOCKS + 9, 256, 0, stream>>>(dst, cnt, fc2W, fc2b, cW[0],
                                                      W2c, b2c);
    k_scan<<<1, 1024, 0, stream>>>(cnt, rowptr, disq, Hb);
    k_fill_fc<<<FC_BLOCKS + FILL_BLOCKS, 256, 0, stream>>>(
        src, dst, rowptr, cnt, esrc, nf, fc1W, fc1b, W2c, b2c, disq, Hb);

    const int cgrid = (NHALF * 64 + 255) / 256;  // one wave per 2 nodes

    // conv1: out1 -> B1
    k_csr_conv<<<cgrid, 256, 0, stream>>>(Hb, rowptr, esrc, disq, cb[0], nullptr, B1, 1);
    // conv2: out2 = lrelu(conv)+out1 -> B0
    k_gemm64<<<512, 256, 0, stream>>>(B1, cW[1], disq, Hb);
    k_csr_conv<<<cgrid, 256, 0, stream>>>(Hb, rowptr, esrc, disq, cb[1], B1, B0, 1);
    // conv3: out3 -> B1
    k_gemm64<<<512, 256, 0, stream>>>(B0, cW[2], disq, Hb);
    k_csr_conv<<<cgrid, 256, 0, stream>>>(Hb, rowptr, esrc, disq, cb[2], nullptr, B1, 1);
    // conv4 + residual(out2=B0) + final projection -> d_out
    k_gemm64<<<512, 256, 0, stream>>>(B1, cW[3], disq, Hb);
    k_csr_conv_final<<<cgrid, 256, 0, stream>>>(Hb, rowptr, esrc, disq, cb[3], B0,
                                                fW, fb, (float*)d_out);
}